// Round 19
// baseline (21.723 us; speedup 1.0000x reference)
//
#include <hip/hip_runtime.h>

// Problem constants (match reference setup_inputs)
#define BATCH    2
#define NPART    4096
#define NTHREADS 512
#define NWAVES   8
#define ITILE    128              // i per block (2 per lane, lane-private)
#define NIT      (NPART / ITILE)  // 32 i-tiles
#define NJS      16               // j-segments -> 16 atomic contenders/address
#define JSEG     (NPART / NJS)    // 256 j per block
#define JPW      (JSEG / NWAVES)  // 32 j per wave (WAVE-UNIFORM stream)

typedef float v2f __attribute__((ext_vector_type(2)));

// One uniform j against this lane's 2 i's. j components are wave-uniform
// (SGPR splats) -> VOP3P takes 1 SGPR operand fine. No local arrays (R15 lesson).
template <bool MASKED>
__device__ inline void lj_j(float jx, float jy, float jz,
                            v2f qx, v2f qy, v2f qz,
                            v2f& fx, v2f& fy, v2f& fz) {
    const v2f dx = qx - (v2f)jx;
    const v2f dy = qy - (v2f)jy;
    const v2f dz = qz - (v2f)jz;
    v2f r2 = dx * dx;
    r2 = __builtin_elementwise_fma(dy, dy, r2);
    r2 = __builtin_elementwise_fma(dz, dz, r2);
    v2f inv;
    if (MASKED) {   // r2==0.0f exactly <=> i==j (reference's mask semantics)
        inv.x = (r2.x > 0.0f) ? __builtin_amdgcn_rcpf(r2.x) : 0.0f;
        inv.y = (r2.y > 0.0f) ? __builtin_amdgcn_rcpf(r2.y) : 0.0f;
    } else {
        inv.x = __builtin_amdgcn_rcpf(r2.x);
        inv.y = __builtin_amdgcn_rcpf(r2.y);
    }
    const v2f inv2 = inv * inv;
    const v2f s6 = inv2 * inv;                                      // sigma = 1
    const v2f c1 = __builtin_elementwise_fma((v2f)48.0f, s6, (v2f)(-24.0f));
    const v2f coeff = (inv * s6) * c1;     // 24*inv*s6*(2*s6-1)
    fx = __builtin_elementwise_fma(coeff, dx, fx);
    fy = __builtin_elementwise_fma(coeff, dy, fy);
    fz = __builtin_elementwise_fma(coeff, dz, fz);
}

// Fully fused single dispatch (plus a 96KB memset for the atomic targets).
// Block: 8 waves share one 128-i tile; lane owns i = tile + 2*lane {+1}.
// Each wave streams a WAVE-UNIFORM 32-j chunk: 1 cache line per j-load
// (vs ~16 lines/load for per-lane chunks -- the R1..R18 hidden TA cost),
// scalarized via readfirstlane so the compiler can emit s_load.
// 1024 blocks x 512 thr = 4 blocks/CU = 8 waves/SIMD. Only the 1/16 of
// blocks with js == it>>1 can see the diagonal.
__global__ __launch_bounds__(NTHREADS, 8) void lj_fused(
        const float* __restrict__ q, const float* __restrict__ p,
        const float* __restrict__ m, float* __restrict__ dq,
        float* __restrict__ dp) {
    __shared__ float red[NWAVES][64][7];   // pad 7: lane-stride coprime w/ 32 banks

    const int it = blockIdx.x;
    const int js = blockIdx.y;
    const int b  = blockIdx.z;
    const int t  = threadIdx.x;
    const int l  = t & 63;
    const int w  = t >> 6;

    const float* qb = q + (size_t)b * NPART * 3;

    // Lane-private i pair (one-time strided load, 3 x float2)
    const int i0 = it * ITILE + 2 * l;
    const float2* qi2 = (const float2*)(qb + (size_t)i0 * 3);
    const float2 a0 = qi2[0];              // x0 y0
    const float2 a1 = qi2[1];              // z0 x1
    const float2 a2 = qi2[2];              // y1 z1
    const v2f qx = {a0.x, a1.y};
    const v2f qy = {a0.y, a2.x};
    const v2f qz = {a1.x, a2.y};

    v2f fx = (v2f)0.0f, fy = (v2f)0.0f, fz = (v2f)0.0f;

    // Wave-uniform j stream (readfirstlane -> scalar pipe)
    const int wv = __builtin_amdgcn_readfirstlane(w);
    const float* jq = qb + (size_t)(js * JSEG + wv * JPW) * 3;

    if (js == (it >> 1)) {                 // diagonal block (1/16)
        #pragma unroll 8
        for (int k = 0; k < JPW; ++k)
            lj_j<true >(jq[3 * k], jq[3 * k + 1], jq[3 * k + 2],
                        qx, qy, qz, fx, fy, fz);
    } else {
        #pragma unroll 8
        for (int k = 0; k < JPW; ++k)
            lj_j<false>(jq[3 * k], jq[3 * k + 1], jq[3 * k + 2],
                        qx, qy, qz, fx, fy, fz);
    }

    // slot = comp*2 + half (i = 2l + half)
    red[w][l][0] = fx.x;  red[w][l][1] = fx.y;
    red[w][l][2] = fy.x;  red[w][l][3] = fy.y;
    red[w][l][4] = fz.x;  red[w][l][5] = fz.y;
    __syncthreads();

    // 384 threads: t = il*3 + c. Sum 8 wave partials, one atomicAdd each
    // (16 contenders per address -- R3-proven safe). js==0 blocks emit dq.
    if (t < 384) {
        const int il = t / 3;              // 0..127
        const int c  = t - 3 * il;         // 0..2
        const int lx = il >> 1;
        const int hx = il & 1;
        float s = 0.0f;
        #pragma unroll
        for (int ww = 0; ww < NWAVES; ++ww) s += red[ww][lx][c * 2 + hx];
        const size_t go = (size_t)b * (NPART * 3) + (size_t)it * (ITILE * 3) + t;
        atomicAdd(&dp[go], s);
        if (js == 0) {
            dq[go] = p[go] / m[go / 3];    // exact IEEE div, tiny count
        }
    }
}

extern "C" void kernel_launch(void* const* d_in, const int* in_sizes, int n_in,
                              void* d_out, int out_size, void* d_ws, size_t ws_size,
                              hipStream_t stream) {
    const float* q = (const float*)d_in[0];
    const float* p = (const float*)d_in[1];
    const float* m = (const float*)d_in[2];
    // d_in[3] = t, unused by the reference outputs

    const int n_elem = BATCH * NPART * 3;   // 24576 per output tensor
    float* dq_out = (float*)d_out;          // first output: dq
    float* dp_out = (float*)d_out + n_elem; // second output: dp

    // dp accumulated via atomics -> zero it every call (graph-capture-safe)
    hipMemsetAsync(dp_out, 0, (size_t)n_elem * sizeof(float), stream);

    dim3 grid(NIT, NJS, BATCH);             // 1024 blocks x 512 threads
    lj_fused<<<grid, NTHREADS, 0, stream>>>(q, p, m, dq_out, dp_out);
}

// Round 20
// 17.527 us; speedup vs baseline: 1.2394x; 1.2394x over previous
//
#include <hip/hip_runtime.h>

// Problem constants (match reference setup_inputs)
// == Round-13 configuration: empirical best (17.5 us) over 19 rounds ==
#define BATCH    2
#define NPART    4096
#define NTHREADS 512
#define IBLK     8                    // i per block
#define ILANES   4                    // lane slots in i-dim (2 i packed per lane)
#define JCH      (NTHREADS / ILANES)  // 128 j-chunks per block
#define JLEN     (NPART / JCH)        // 32 j per chunk
#define NIB      (NPART / IBLK)       // 512 i-blocks per batch

typedef float v2f __attribute__((ext_vector_type(2)));

// One (j, 2-i) interaction; v2f packs the two i's. MASKED handles i==j (r2==0).
// All by value / scalar-ref -- no local arrays (R14/R15 scratch lesson).
template <bool MASKED>
__device__ inline void lj_body(float jx, float jy, float jz,
                               v2f qx, v2f qy, v2f qz,
                               v2f& fx, v2f& fy, v2f& fz) {
    const v2f dx = qx - (v2f)jx;
    const v2f dy = qy - (v2f)jy;
    const v2f dz = qz - (v2f)jz;
    v2f r2 = dx * dx;
    r2 = __builtin_elementwise_fma(dy, dy, r2);
    r2 = __builtin_elementwise_fma(dz, dz, r2);
    v2f inv;
    if (MASKED) {   // r2==0.0f exactly <=> i==j (reference's mask semantics)
        inv.x = (r2.x > 0.0f) ? __builtin_amdgcn_rcpf(r2.x) : 0.0f;
        inv.y = (r2.y > 0.0f) ? __builtin_amdgcn_rcpf(r2.y) : 0.0f;
    } else {
        inv.x = __builtin_amdgcn_rcpf(r2.x);
        inv.y = __builtin_amdgcn_rcpf(r2.y);
    }
    const v2f inv2 = inv * inv;
    const v2f s6 = inv2 * inv;                                      // sigma = 1
    const v2f c1 = __builtin_elementwise_fma((v2f)48.0f, s6, (v2f)(-24.0f));
    const v2f coeff = (inv * s6) * c1;     // 24*inv*s6*(2*s6-1)
    fx = __builtin_elementwise_fma(coeff, dx, fx);
    fy = __builtin_elementwise_fma(coeff, dy, fy);
    fz = __builtin_elementwise_fma(coeff, dz, fz);
}

template <bool MASKED>
__device__ inline void chunk_loop(const float4* __restrict__ jq4,
                                  v2f qx, v2f qy, v2f qz,
                                  v2f& fx, v2f& fy, v2f& fz) {
    #pragma unroll
    for (int it = 0; it < JLEN / 4; ++it) {
        const float4 A = jq4[3 * it + 0];   // x0 y0 z0 x1
        const float4 B = jq4[3 * it + 1];   // y1 z1 x2 y2
        const float4 C = jq4[3 * it + 2];   // z2 x3 y3 z3
        lj_body<MASKED>(A.x, A.y, A.z, qx, qy, qz, fx, fy, fz);
        lj_body<MASKED>(A.w, B.x, B.y, qx, qy, qz, fx, fy, fz);
        lj_body<MASKED>(B.z, B.w, C.x, qx, qy, qz, fx, fy, fz);
        lj_body<MASKED>(C.y, C.z, C.w, qx, qy, qz, fx, fy, fz);
    }
}

// Fully fused single dispatch. Block owns 8 i's x all 4096 j (128 chunks of 32
// across lanes); LDS reduction. 1024 blocks x 512 thr -> 4 blocks/CU,
// 8 waves/SIMD. Only wave (ib>>6) can contain the diagonal -> 7/8 waves
// run maskless bodies.
__global__ __launch_bounds__(NTHREADS, 8) void lj_fused(
        const float* __restrict__ q, const float* __restrict__ p,
        const float* __restrict__ m, float* __restrict__ dq,
        float* __restrict__ dp) {
    __shared__ float red[JCH * 6 * ILANES];   // 12 KB
    __shared__ float red2[24 * 8];            // stage-1 partials

    const int ib = blockIdx.x;
    const int b  = blockIdx.y;
    const int t  = threadIdx.x;
    const int il = t & (ILANES - 1);
    const int jc = t >> 2;                    // 0..127

    const float* qb = q + (size_t)b * NPART * 3;

    const int i0 = ib * IBLK + il;            // first i of this lane
    const int i1 = i0 + ILANES;               // second i of this lane
    const v2f qx = {qb[i0 * 3 + 0], qb[i1 * 3 + 0]};
    const v2f qy = {qb[i0 * 3 + 1], qb[i1 * 3 + 1]};
    const v2f qz = {qb[i0 * 3 + 2], qb[i1 * 3 + 2]};

    v2f fx = (v2f)0.0f, fy = (v2f)0.0f, fz = (v2f)0.0f;

    const float4* jq4 = (const float4*)(qb + (size_t)jc * JLEN * 3);

    // Block's 8 i's all live in j-chunk (ib>>2) -> only wave (ib>>6) masked.
    if ((t >> 6) == (ib >> 6)) {
        chunk_loop<true >(jq4, qx, qy, qz, fx, fy, fz);
    } else {
        chunk_loop<false>(jq4, qx, qy, qz, fx, fy, fz);
    }

    // Stash 6 partials (2 i-halves x 3 comps): slot = c*2+h
    red[(jc * 6 + 0) * ILANES + il] = fx.x;
    red[(jc * 6 + 1) * ILANES + il] = fx.y;
    red[(jc * 6 + 2) * ILANES + il] = fy.x;
    red[(jc * 6 + 3) * ILANES + il] = fy.y;
    red[(jc * 6 + 4) * ILANES + il] = fz.x;
    red[(jc * 6 + 5) * ILANES + il] = fz.y;
    __syncthreads();

    // Stage 1: 192 threads, each sums 16 of the 128 chunk partials.
    if (t < 192) {
        const int sl = t >> 3;         // 0..23: slot*4 + il
        const int g  = t & 7;          // 0..7: group of 16 chunks
        const int slot = sl >> 2;
        const int il2  = sl & 3;
        float s = 0.0f;
        #pragma unroll
        for (int qq = 0; qq < 16; ++qq) {
            s += red[((g * 16 + qq) * 6 + slot) * ILANES + il2];
        }
        red2[sl * 8 + g] = s;
    }
    __syncthreads();

    // Stage 2: 24 threads -> one (c, i-in-block) each; fuse dq = p/m.
    if (t < 24) {
        float s = 0.0f;
        #pragma unroll
        for (int g = 0; g < 8; ++g) s += red2[t * 8 + g];
        const int slot = t >> 2;       // c*2 + h
        const int il2  = t & 3;
        const int c  = slot >> 1;
        const int h  = slot & 1;
        const int ii = h * ILANES + il2;
        const size_t gi = (size_t)b * NPART + ib * IBLK + ii;
        dp[gi * 3 + c] = s;
        dq[gi * 3 + c] = p[gi * 3 + c] / m[gi];   // exact IEEE div, tiny count
    }
}

extern "C" void kernel_launch(void* const* d_in, const int* in_sizes, int n_in,
                              void* d_out, int out_size, void* d_ws, size_t ws_size,
                              hipStream_t stream) {
    const float* q = (const float*)d_in[0];
    const float* p = (const float*)d_in[1];
    const float* m = (const float*)d_in[2];
    // d_in[3] = t, unused by the reference outputs

    const int n_elem = BATCH * NPART * 3;   // 24576 per output tensor
    float* dq_out = (float*)d_out;          // first output: dq
    float* dp_out = (float*)d_out + n_elem; // second output: dp

    dim3 grid(NIB, BATCH);                  // 1024 blocks x 512 threads
    lj_fused<<<grid, NTHREADS, 0, stream>>>(q, p, m, dq_out, dp_out);
}